// Round 2
// baseline (518.616 us; speedup 1.0000x reference)
//
#include <hip/hip_runtime.h>

// ---------------------------------------------------------------------------
// DifferentiableTreeDense: out[b, l*128+o] =
//    leaf_prob[b,l] * (dot(x[b,:], leaf_w[l,:,o]) + bias[l,o])
//
// leaf_gemm: 256² 8-phase template (T1 XCD swizzle + T2 st_16x32 LDS swizzle +
// T3/T4 counted-vmcnt phases + T5 setprio). BM=BN=256, BK=64, 8 waves.
// ---------------------------------------------------------------------------

typedef __attribute__((ext_vector_type(8))) short short8;
typedef __attribute__((ext_vector_type(4))) float f32x4;

#define BATCH 8192
#define FEAT  1024
#define NLEAF 64
#define LEAFD 128
#define OUTD  8192

#define BM 256
#define BN 256
#define BK 64
#define NT (FEAT / BK)   // 16 K-tiles

__device__ __forceinline__ unsigned short f2bf(float f) {
    union { float f; unsigned int u; } c; c.f = f;
    unsigned int u = c.u;
    return (unsigned short)((u + 0x7FFFu + ((u >> 16) & 1u)) >> 16);  // RNE
}

__device__ __forceinline__ void gload16(const void* g, void* l) {
    // async global->LDS, 16B per lane. LDS dest must be wave-uniform base + lane*16.
    __builtin_amdgcn_global_load_lds(
        (const __attribute__((address_space(1))) unsigned int*)g,
        (__attribute__((address_space(3))) unsigned int*)l, 16, 0, 0);
}

// --------------------------- conversion kernels ----------------------------

__global__ __launch_bounds__(256) void cvt_x(const float* __restrict__ x,
                                             unsigned short* __restrict__ xb) {
    const int i = (blockIdx.x * 256 + threadIdx.x) * 4;
    const float4 v = *(const float4*)(x + i);
    ushort4 o;
    o.x = f2bf(v.x); o.y = f2bf(v.y); o.z = f2bf(v.z); o.w = f2bf(v.w);
    *(ushort4*)(xb + i) = o;
}

// leaf_weights fp32 [64][1024][128] -> bf16 transposed [64][128][1024]
// (leaf-major concat == [8192][1024] with row = global output column)
__global__ __launch_bounds__(256) void cvt_lw(const float* __restrict__ lw,
                                              unsigned short* __restrict__ wt) {
    __shared__ float tile[32][33];
    const int l  = blockIdx.x;
    const int k0 = blockIdx.y * 32;
    const int o0 = blockIdx.z * 32;
    const int tr = threadIdx.x >> 5;
    const int tc = threadIdx.x & 31;
    const float* src = lw + (size_t)l * (FEAT * LEAFD);
#pragma unroll
    for (int p = 0; p < 4; ++p) {
        const int r = p * 8 + tr;
        tile[r][tc] = src[(size_t)(k0 + r) * LEAFD + o0 + tc];
    }
    __syncthreads();
    unsigned short* dst = wt + (size_t)l * (LEAFD * FEAT);
#pragma unroll
    for (int p = 0; p < 4; ++p) {
        const int oo = p * 8 + tr;
        dst[(size_t)(o0 + oo) * FEAT + k0 + tc] = f2bf(tile[tc][oo]);
    }
}

__global__ __launch_bounds__(256) void cvt_rw(const float* __restrict__ rw,
                                              unsigned short* __restrict__ rt) {
    const int gid = blockIdx.x * 256 + threadIdx.x;
    const int row = gid >> 10;
    const int f   = gid & 1023;
    const float v = (row < 126) ? rw[(size_t)(row >> 1) * 2048 + f * 2 + (row & 1)] : 0.0f;
    rt[gid] = f2bf(v);
}

// ----------------------------- routing GEMM --------------------------------
__global__ __launch_bounds__(256) void routing_gemm(
        const unsigned short* __restrict__ xb,
        const unsigned short* __restrict__ rt,
        float* __restrict__ logits) {
    __shared__ __align__(16) unsigned short As[128 * 32];
    __shared__ __align__(16) unsigned short Bs[128 * 32];
    const int t    = threadIdx.x;
    const int row0 = blockIdx.x * 128;
    const int wv = t >> 6, ln = t & 63;
    const int wm = wv >> 1, wn = wv & 1;
    const int quad = ln >> 4, r16 = ln & 15;

    f32x4 acc[4][4];
#pragma unroll
    for (int i = 0; i < 4; ++i)
#pragma unroll
        for (int j = 0; j < 4; ++j) acc[i][j] = (f32x4)0.0f;

    const unsigned short* ag = xb + (size_t)row0 * FEAT;
    const int srow = t >> 2;
    const int scol = (t & 3) * 8;

    for (int k0 = 0; k0 < FEAT; k0 += 32) {
#pragma unroll
        for (int i = 0; i < 2; ++i) {
            gload16(ag + (size_t)(i * 64 + srow) * FEAT + k0 + scol,
                    (char*)As + i * 4096 + t * 16);
            gload16(rt + (size_t)(i * 64 + srow) * FEAT + k0 + scol,
                    (char*)Bs + i * 4096 + t * 16);
        }
        __syncthreads();
        short8 a[4], b[4];
#pragma unroll
        for (int mi = 0; mi < 4; ++mi)
            a[mi] = *(const short8*)&As[(wm * 64 + mi * 16 + r16) * 32 + quad * 8];
#pragma unroll
        for (int ni = 0; ni < 4; ++ni)
            b[ni] = *(const short8*)&Bs[(wn * 64 + ni * 16 + r16) * 32 + quad * 8];
#pragma unroll
        for (int mi = 0; mi < 4; ++mi)
#pragma unroll
            for (int ni = 0; ni < 4; ++ni)
                acc[mi][ni] = __builtin_amdgcn_mfma_f32_16x16x32_bf16(
                    a[mi], b[ni], acc[mi][ni], 0, 0, 0);
        __syncthreads();
    }
#pragma unroll
    for (int mi = 0; mi < 4; ++mi) {
        const int r = wm * 64 + mi * 16 + quad * 4;
#pragma unroll
        for (int ni = 0; ni < 4; ++ni) {
            const int c = wn * 64 + ni * 16 + r16;
#pragma unroll
            for (int reg = 0; reg < 4; ++reg)
                logits[(size_t)(row0 + r + reg) * 128 + c] = acc[mi][ni][reg];
        }
    }
}

// ------------------------- leaf probabilities ------------------------------
__global__ __launch_bounds__(256) void leafprob(
        const float* __restrict__ logits,
        const int* __restrict__ pnodes,
        const int* __restrict__ pdirs,
        float* __restrict__ lp) {
    const int gid  = blockIdx.x * 256 + threadIdx.x;
    const int b    = gid >> 6;
    const int leaf = gid & 63;
    float prod = 1.0f;
#pragma unroll
    for (int d = 0; d < 6; ++d) {
        const int n   = pnodes[leaf * 6 + d];
        const int dir = pdirs[leaf * 6 + d];
        if (n >= 0) {
            const float z0 = logits[(size_t)b * 128 + n * 2];
            const float z1 = logits[(size_t)b * 128 + n * 2 + 1];
            const float zd = dir ? z1 : z0;
            const float zo = dir ? z0 : z1;
            prod *= 1.0f / (1.0f + __expf(zo - zd));
        }
    }
    lp[gid] = prod;
}

// ------------------------------ main GEMM ----------------------------------
// 256x256 tile, BK=64, 8 waves (2M x 4N), double-buffered 128KB LDS with
// st_16x32 swizzle, 4 phases/K-tile, counted vmcnt(4), setprio around MFMA.
//
// Half-tile stage ledger (steady state, iteration kt):
//   P1: stage A0(kt+1) -> Abuf[kt+1]   (A regions of the other buffer: free)
//   P2: stage A1(kt+1) -> Abuf[kt+1]
//   P3: stage B0(kt+2) -> Bbuf[kt]     (B of current buffer dead after P2)
//   P4: stage B1(kt+2) -> Bbuf[kt]; vmcnt(4) guarantees tile kt+1 arrived
//       (only B0/B1(kt+2) = 4 loads stay in flight), barrier.
__global__ __launch_bounds__(512, 2) void leaf_gemm(
        const unsigned short* __restrict__ xb,   // [8192][1024] bf16
        const unsigned short* __restrict__ wt,   // [8192][1024] bf16 (leaf concat)
        const float* __restrict__ lp,            // [8192][64]
        const float* __restrict__ bias,          // [64][128]
        float* __restrict__ out) {               // [8192][8192]
    __shared__ __align__(16) char lds[134144];
    char* Abuf = lds;                              // 2 x 32KB
    char* Bbuf = lds + 65536;                      // 2 x 32KB
    float* lps = (float*)(lds + 131072);           // [2][256]
    float* bs  = (float*)(lds + 133120);           // [256]

    const int t = threadIdx.x;                     // 0..511

    // T1: bijective XCD swizzle (1024 wgs % 8 == 0)
    const int wg  = blockIdx.x;
    const int swz = (wg & 7) * 128 + (wg >> 3);
    const int by  = swz >> 5;                      // column tile 0..31
    const int bx  = swz & 31;                      // row tile 0..31
    const int row0 = bx * BM;
    const int col0 = by * BN;
    const int l0   = by * 2;                       // 2 leaves per 256-col tile

    // epilogue tables
    {
        const int j = t >> 8, r = t & 255;
        lps[j * 256 + r] = lp[(size_t)(row0 + r) * NLEAF + l0 + j];
        if (t < 256) bs[t] = bias[l0 * LEAFD + t];
    }

    // ---- staging geometry: inverse st_16x32 swizzle.
    // phys layout per 128x64 half-tile: 16 subtiles of [16][32] bf16 (1KB),
    // within subtile: byte = r*64 + (c ^ (r&8 ? 16 : 0))*2.
    // chunk q (16B) -> logical (row,col) so linear global_load_lds lands swizzled.
    int goff0, goff1;
    {
#pragma unroll
        for (int i = 0; i < 2; ++i) {
            const int q   = t + i * 512;           // 0..1023
            const int sub = q >> 6;                // subtile ordinal 0..15
            const int qq  = q & 63;
            const int r   = qq >> 2;               // 0..15
            const int cc  = (qq & 3) * 8;          // 0,8,16,24
            const int row = (sub >> 1) * 16 + r;
            const int col = (sub & 1) * 32 + (cc ^ ((r & 8) ? 16 : 0));
            const int off = row * FEAT + col;
            if (i == 0) goff0 = off; else goff1 = off;
        }
    }

    const unsigned short* Ag = xb + (size_t)row0 * FEAT;
    const unsigned short* Bg = wt + (size_t)col0 * FEAT;

// stage one 128x64 half-tile (2 x global_load_lds per thread)
#define STAGE(gbase, ldsbase, bufsel, h, kt)                                   \
    do {                                                                       \
        gload16(gbase + (h) * 131072 + (kt) * BK + goff0,                      \
                (ldsbase) + (bufsel) * 32768 + (h) * 16384 + t * 16);          \
        gload16(gbase + (h) * 131072 + (kt) * BK + goff1,                      \
                (ldsbase) + (bufsel) * 32768 + (h) * 16384 + 8192 + t * 16);   \
    } while (0)

    // wave / lane decomposition: 8 waves = 2 (M) x 4 (N); per-wave 128x64 out
    const int wv   = t >> 6;
    const int ln   = t & 63;
    const int wm   = wv >> 2;      // 0..1
    const int wn   = wv & 3;       // 0..3
    const int quad = ln >> 4;      // 0..3
    const int r16  = ln & 15;

    // swizzled per-lane fragment byte base within a subtile
    const int fb = r16 * 64 + ((quad * 8) ^ ((r16 & 8) << 1)) * 2;
    const char* Afb = Abuf + wm * 16384 + fb;   // + cur*32768 + mi*2048 + ks*1024
    const char* Bfb = Bbuf + wn * 8192 + fb;    // + cur*32768 + ni*2048 + ks*1024

    f32x4 acc[8][4];
#pragma unroll
    for (int i = 0; i < 8; ++i)
#pragma unroll
        for (int j = 0; j < 4; ++j) acc[i][j] = (f32x4)0.0f;

    // prologue: B0(0) B1(0) A0(0) A1(0) B0(1) B1(1); keep newest 4 loads flying
    STAGE(Bg, Bbuf, 0, 0, 0);
    STAGE(Bg, Bbuf, 0, 1, 0);
    STAGE(Ag, Abuf, 0, 0, 0);
    STAGE(Ag, Abuf, 0, 1, 0);
    STAGE(Bg, Bbuf, 1, 0, 1);
    STAGE(Bg, Bbuf, 1, 1, 1);
    asm volatile("s_waitcnt vmcnt(4)" ::: "memory");
    __builtin_amdgcn_s_barrier();

    short8 a[4][2], b01[2][2], b23[2][2];

#pragma unroll 2
    for (int kt = 0; kt < NT; ++kt) {
        const int cur = kt & 1;
        const char* Ac = Afb + cur * 32768;
        const char* Bc = Bfb + cur * 32768;

        // ---- phase 1: read A(mi 0-3) + B(ni 0-1); stage A0(kt+1); MFMA Q00
#pragma unroll
        for (int mi = 0; mi < 4; ++mi)
#pragma unroll
            for (int ks = 0; ks < 2; ++ks)
                a[mi][ks] = *(const short8*)(Ac + mi * 2048 + ks * 1024);
#pragma unroll
        for (int ni = 0; ni < 2; ++ni)
#pragma unroll
            for (int ks = 0; ks < 2; ++ks)
                b01[ni][ks] = *(const short8*)(Bc + ni * 2048 + ks * 1024);
        if (kt + 1 < NT) STAGE(Ag, Abuf, (kt + 1) & 1, 0, kt + 1);
        __builtin_amdgcn_s_barrier();
        asm volatile("s_waitcnt lgkmcnt(0)" ::: "memory");
        __builtin_amdgcn_s_setprio(1);
#pragma unroll
        for (int mi = 0; mi < 4; ++mi)
#pragma unroll
            for (int ni = 0; ni < 2; ++ni)
#pragma unroll
                for (int ks = 0; ks < 2; ++ks)
                    acc[mi][ni] = __builtin_amdgcn_mfma_f32_16x16x32_bf16(
                        a[mi][ks], b01[ni][ks], acc[mi][ni], 0, 0, 0);
        __builtin_amdgcn_s_setprio(0);
        __builtin_amdgcn_s_barrier();

        // ---- phase 2: read B(ni 2-3); stage A1(kt+1); MFMA Q01
#pragma unroll
        for (int ni = 0; ni < 2; ++ni)
#pragma unroll
            for (int ks = 0; ks < 2; ++ks)
                b23[ni][ks] = *(const short8*)(Bc + (ni + 2) * 2048 + ks * 1024);
        if (kt + 1 < NT) STAGE(Ag, Abuf, (kt + 1) & 1, 1, kt + 1);
        __builtin_amdgcn_s_barrier();
        asm volatile("s_waitcnt lgkmcnt(0)" ::: "memory");
        __builtin_amdgcn_s_setprio(1);
#pragma unroll
        for (int mi = 0; mi < 4; ++mi)
#pragma unroll
            for (int ni = 0; ni < 2; ++ni)
#pragma unroll
                for (int ks = 0; ks < 2; ++ks)
                    acc[mi][ni + 2] = __builtin_amdgcn_mfma_f32_16x16x32_bf16(
                        a[mi][ks], b23[ni][ks], acc[mi][ni + 2], 0, 0, 0);
        __builtin_amdgcn_s_setprio(0);
        __builtin_amdgcn_s_barrier();

        // ---- phase 3: read A(mi 4-7); stage B0(kt+2); MFMA Q10 (b01 held)
#pragma unroll
        for (int mi = 0; mi < 4; ++mi)
#pragma unroll
            for (int ks = 0; ks < 2; ++ks)
                a[mi][ks] = *(const short8*)(Ac + (mi + 4) * 2048 + ks * 1024);
        if (kt + 2 < NT) STAGE(Bg, Bbuf, kt & 1, 0, kt + 2);
        __builtin_amdgcn_s_barrier();
        asm volatile("s_waitcnt lgkmcnt(0)" ::: "memory");
        __builtin_amdgcn_s_setprio(1);
#pragma unroll
        for (int mi = 0; mi < 4; ++mi)
#pragma unroll
            for (int ni = 0; ni < 2; ++ni)
#pragma unroll
                for (int ks = 0; ks < 2; ++ks)
                    acc[mi + 4][ni] = __builtin_amdgcn_mfma_f32_16x16x32_bf16(
                        a[mi][ks], b01[ni][ks], acc[mi + 4][ni], 0, 0, 0);
        __builtin_amdgcn_s_setprio(0);
        __builtin_amdgcn_s_barrier();

        // ---- phase 4: stage B1(kt+2); MFMA Q11; counted vmcnt; barrier
        if (kt + 2 < NT) STAGE(Bg, Bbuf, kt & 1, 1, kt + 2);
        __builtin_amdgcn_s_barrier();
        __builtin_amdgcn_s_setprio(1);
#pragma unroll
        for (int mi = 0; mi < 4; ++mi)
#pragma unroll
            for (int ni = 0; ni < 2; ++ni)
#pragma unroll
                for (int ks = 0; ks < 2; ++ks)
                    acc[mi + 4][ni + 2] = __builtin_amdgcn_mfma_f32_16x16x32_bf16(
                        a[mi][ks], b23[ni][ks], acc[mi + 4][ni + 2], 0, 0, 0);
        __builtin_amdgcn_s_setprio(0);
        if (kt + 2 < NT) {
            asm volatile("s_waitcnt vmcnt(4)" ::: "memory");   // tile kt+1 arrived
        } else if (kt + 1 < NT) {
            asm volatile("s_waitcnt vmcnt(0)" ::: "memory");   // epilogue drain
        }
        __builtin_amdgcn_s_barrier();
    }
#undef STAGE

    // epilogue: (acc + bias) * leaf_prob, nontemporal streaming stores
    const float* lpw = lps + (wn >> 1) * 256;
#pragma unroll
    for (int mi = 0; mi < 8; ++mi) {
        const int r = wm * 128 + mi * 16 + quad * 4;
#pragma unroll
        for (int ni = 0; ni < 4; ++ni) {
            const int c  = wn * 64 + ni * 16 + r16;
            const float bv = bs[c];
#pragma unroll
            for (int reg = 0; reg < 4; ++reg) {
                const float v = (acc[mi][ni][reg] + bv) * lpw[r + reg];
                __builtin_nontemporal_store(
                    v, &out[(size_t)(row0 + r + reg) * OUTD + col0 + c]);
            }
        }
    }
}

// ------------------------------- launcher ----------------------------------

extern "C" void kernel_launch(void* const* d_in, const int* in_sizes, int n_in,
                              void* d_out, int out_size, void* d_ws, size_t ws_size,
                              hipStream_t stream) {
    const float* x    = (const float*)d_in[0];   // [8192][1024]
    const float* rw   = (const float*)d_in[1];   // [63][1024][2]
    const float* lw   = (const float*)d_in[2];   // [64][1024][128]
    const float* bias = (const float*)d_in[3];   // [64][128]
    const int*   pn   = (const int*)d_in[4];     // [64][6]
    const int*   pd   = (const int*)d_in[5];     // [64][6]
    float* out = (float*)d_out;

    char* ws = (char*)d_ws;
    unsigned short* xb     = (unsigned short*)(ws);               // 16 MB
    unsigned short* wt     = (unsigned short*)(ws + 16777216);    // 16 MB
    unsigned short* rt     = (unsigned short*)(ws + 33554432);    // 256 KB
    float*          logits = (float*)(ws + 33816576);             // 4 MB
    float*          lpv    = (float*)(ws + 38010880);             // 2 MB

    cvt_x<<<8192, 256, 0, stream>>>(x, xb);
    cvt_lw<<<dim3(64, 32, 4), 256, 0, stream>>>(lw, wt);
    cvt_rw<<<512, 256, 0, stream>>>(rw, rt);
    routing_gemm<<<64, 256, 0, stream>>>(xb, rt, logits);
    leafprob<<<2048, 256, 0, stream>>>(logits, pn, pd, lpv);
    leaf_gemm<<<1024, 512, 0, stream>>>(xb, wt, lpv, bias, out);
}

// Round 3
// 513.511 us; speedup vs baseline: 1.0099x; 1.0099x over previous
//
#include <hip/hip_runtime.h>

// ---------------------------------------------------------------------------
// DifferentiableTreeDense: out[b, l*128+o] =
//    leaf_prob[b,l] * (dot(x[b,:], leaf_w[l,:,o]) + bias[l,o])
//
// leaf_gemm: 256² tile, BK=64, 8 waves, T1 XCD swizzle + T2 st_16x32 swizzle
// + counted vmcnt. Round-2 restructure: 2 barriers/K-tile, fragment reads
// issued ahead of their MFMA cluster (drain hides under previous MFMA run),
// a47 re-reads reuse a03 registers to keep total regs <= 248 (2 waves/SIMD).
// ---------------------------------------------------------------------------

typedef __attribute__((ext_vector_type(8))) short short8;
typedef __attribute__((ext_vector_type(4))) float f32x4;

#define BATCH 8192
#define FEAT  1024
#define NLEAF 64
#define LEAFD 128
#define OUTD  8192

#define BM 256
#define BN 256
#define BK 64
#define NT (FEAT / BK)   // 16 K-tiles

__device__ __forceinline__ unsigned short f2bf(float f) {
    union { float f; unsigned int u; } c; c.f = f;
    unsigned int u = c.u;
    return (unsigned short)((u + 0x7FFFu + ((u >> 16) & 1u)) >> 16);  // RNE
}

__device__ __forceinline__ void gload16(const void* g, void* l) {
    // async global->LDS, 16B per lane. LDS dest must be wave-uniform base + lane*16.
    __builtin_amdgcn_global_load_lds(
        (const __attribute__((address_space(1))) unsigned int*)g,
        (__attribute__((address_space(3))) unsigned int*)l, 16, 0, 0);
}

// --------------------------- conversion kernels ----------------------------

__global__ __launch_bounds__(256) void cvt_x(const float* __restrict__ x,
                                             unsigned short* __restrict__ xb) {
    const int i = (blockIdx.x * 256 + threadIdx.x) * 4;
    const float4 v = *(const float4*)(x + i);
    ushort4 o;
    o.x = f2bf(v.x); o.y = f2bf(v.y); o.z = f2bf(v.z); o.w = f2bf(v.w);
    *(ushort4*)(xb + i) = o;
}

// leaf_weights fp32 [64][1024][128] -> bf16 transposed [64][128][1024]
__global__ __launch_bounds__(256) void cvt_lw(const float* __restrict__ lw,
                                              unsigned short* __restrict__ wt) {
    __shared__ float tile[32][33];
    const int l  = blockIdx.x;
    const int k0 = blockIdx.y * 32;
    const int o0 = blockIdx.z * 32;
    const int tr = threadIdx.x >> 5;
    const int tc = threadIdx.x & 31;
    const float* src = lw + (size_t)l * (FEAT * LEAFD);
#pragma unroll
    for (int p = 0; p < 4; ++p) {
        const int r = p * 8 + tr;
        tile[r][tc] = src[(size_t)(k0 + r) * LEAFD + o0 + tc];
    }
    __syncthreads();
    unsigned short* dst = wt + (size_t)l * (LEAFD * FEAT);
#pragma unroll
    for (int p = 0; p < 4; ++p) {
        const int oo = p * 8 + tr;
        dst[(size_t)(o0 + oo) * FEAT + k0 + tc] = f2bf(tile[tc][oo]);
    }
}

__global__ __launch_bounds__(256) void cvt_rw(const float* __restrict__ rw,
                                              unsigned short* __restrict__ rt) {
    const int gid = blockIdx.x * 256 + threadIdx.x;
    const int row = gid >> 10;
    const int f   = gid & 1023;
    const float v = (row < 126) ? rw[(size_t)(row >> 1) * 2048 + f * 2 + (row & 1)] : 0.0f;
    rt[gid] = f2bf(v);
}

// ----------------------------- routing GEMM --------------------------------
__global__ __launch_bounds__(256) void routing_gemm(
        const unsigned short* __restrict__ xb,
        const unsigned short* __restrict__ rt,
        float* __restrict__ logits) {
    __shared__ __align__(16) unsigned short As[128 * 32];
    __shared__ __align__(16) unsigned short Bs[128 * 32];
    const int t    = threadIdx.x;
    const int row0 = blockIdx.x * 128;
    const int wv = t >> 6, ln = t & 63;
    const int wm = wv >> 1, wn = wv & 1;
    const int quad = ln >> 4, r16 = ln & 15;

    f32x4 acc[4][4];
#pragma unroll
    for (int i = 0; i < 4; ++i)
#pragma unroll
        for (int j = 0; j < 4; ++j) acc[i][j] = (f32x4)0.0f;

    const unsigned short* ag = xb + (size_t)row0 * FEAT;
    const int srow = t >> 2;
    const int scol = (t & 3) * 8;

    for (int k0 = 0; k0 < FEAT; k0 += 32) {
#pragma unroll
        for (int i = 0; i < 2; ++i) {
            gload16(ag + (size_t)(i * 64 + srow) * FEAT + k0 + scol,
                    (char*)As + i * 4096 + t * 16);
            gload16(rt + (size_t)(i * 64 + srow) * FEAT + k0 + scol,
                    (char*)Bs + i * 4096 + t * 16);
        }
        __syncthreads();
        short8 a[4], b[4];
#pragma unroll
        for (int mi = 0; mi < 4; ++mi)
            a[mi] = *(const short8*)&As[(wm * 64 + mi * 16 + r16) * 32 + quad * 8];
#pragma unroll
        for (int ni = 0; ni < 4; ++ni)
            b[ni] = *(const short8*)&Bs[(wn * 64 + ni * 16 + r16) * 32 + quad * 8];
#pragma unroll
        for (int mi = 0; mi < 4; ++mi)
#pragma unroll
            for (int ni = 0; ni < 4; ++ni)
                acc[mi][ni] = __builtin_amdgcn_mfma_f32_16x16x32_bf16(
                    a[mi], b[ni], acc[mi][ni], 0, 0, 0);
        __syncthreads();
    }
#pragma unroll
    for (int mi = 0; mi < 4; ++mi) {
        const int r = wm * 64 + mi * 16 + quad * 4;
#pragma unroll
        for (int ni = 0; ni < 4; ++ni) {
            const int c = wn * 64 + ni * 16 + r16;
#pragma unroll
            for (int reg = 0; reg < 4; ++reg)
                logits[(size_t)(row0 + r + reg) * 128 + c] = acc[mi][ni][reg];
        }
    }
}

// ------------------------- leaf probabilities ------------------------------
__global__ __launch_bounds__(256) void leafprob(
        const float* __restrict__ logits,
        const int* __restrict__ pnodes,
        const int* __restrict__ pdirs,
        float* __restrict__ lp) {
    const int gid  = blockIdx.x * 256 + threadIdx.x;
    const int b    = gid >> 6;
    const int leaf = gid & 63;
    float prod = 1.0f;
#pragma unroll
    for (int d = 0; d < 6; ++d) {
        const int n   = pnodes[leaf * 6 + d];
        const int dir = pdirs[leaf * 6 + d];
        if (n >= 0) {
            const float z0 = logits[(size_t)b * 128 + n * 2];
            const float z1 = logits[(size_t)b * 128 + n * 2 + 1];
            const float zd = dir ? z1 : z0;
            const float zo = dir ? z0 : z1;
            prod *= 1.0f / (1.0f + __expf(zo - zd));
        }
    }
    lp[gid] = prod;
}

// ------------------------------ main GEMM ----------------------------------
// 256x256 tile, BK=64, 8 waves (2M x 4N), 2x double-buffered 128KB LDS,
// st_16x32 swizzle. Round-2 schedule — 2 barriers per K-tile:
//
//   P1 : ds_read a03(8) + b01(4) + b23(4); STAGE A0(kt+1)
//        [lgkm drain — the ONE exposed wait]; Q00 (16 MFMA)
//        lgkmcnt(0); BAR-A   (certifies all waves' B-reads of tile kt)
//   P2+: STAGE A1(kt+1), B0(kt+2); Q01 (operands resident, zero wait)
//        ds_read a47(8) INTO a03's registers (frag peak stays 64 VGPR)
//        STAGE B1(kt+2); lgkmcnt(0); Q10+Q11 (32 MFMA run)
//   end: vmcnt(4) [tail: vmcnt(0)]; BAR-END
//
// Ledger at vmcnt(4) of kt: queue = [B(kt+1) staged kt-1, A(kt+1) staged kt,
// B(kt+2) staged kt] = 12 loads -> drains A/B(kt+1), leaves B(kt+2). ✓
// Staging safety: A(kt+1) targets buf of A(kt-1), whose last reads (a47)
// were drained before each wave's Q10 and certified by BAR-END of kt-1.
// B(kt+2) targets buf of B(kt), whose reads (P1) are certified by BAR-A.
__global__ __launch_bounds__(512, 2) void leaf_gemm(
        const unsigned short* __restrict__ xb,   // [8192][1024] bf16
        const unsigned short* __restrict__ wt,   // [8192][1024] bf16 (leaf concat)
        const float* __restrict__ lp,            // [8192][64]
        const float* __restrict__ bias,          // [64][128]
        float* __restrict__ out) {               // [8192][8192]
    __shared__ __align__(16) char lds[134144];
    char* Abuf = lds;                              // 2 x 32KB
    char* Bbuf = lds + 65536;                      // 2 x 32KB
    float* lps = (float*)(lds + 131072);           // [2][256]
    float* bs  = (float*)(lds + 133120);           // [256]

    const int t = threadIdx.x;                     // 0..511

    // T1: bijective XCD swizzle (1024 wgs % 8 == 0)
    const int wg  = blockIdx.x;
    const int swz = (wg & 7) * 128 + (wg >> 3);
    const int by  = swz >> 5;                      // column tile 0..31
    const int bx  = swz & 31;                      // row tile 0..31
    const int row0 = bx * BM;
    const int col0 = by * BN;
    const int l0   = by * 2;                       // 2 leaves per 256-col tile

    // epilogue tables (loads fully drained below, before the stage ledger starts)
    {
        const int j = t >> 8, r = t & 255;
        lps[j * 256 + r] = lp[(size_t)(row0 + r) * NLEAF + l0 + j];
        if (t < 256) bs[t] = bias[l0 * LEAFD + t];
    }
    asm volatile("s_waitcnt vmcnt(0)" ::: "memory");  // keep vmcnt ledger clean

    // ---- staging geometry: inverse st_16x32 swizzle.
    int goff0, goff1;
    {
#pragma unroll
        for (int i = 0; i < 2; ++i) {
            const int q   = t + i * 512;           // 0..1023
            const int sub = q >> 6;                // subtile ordinal 0..15
            const int qq  = q & 63;
            const int r   = qq >> 2;               // 0..15
            const int cc  = (qq & 3) * 8;          // 0,8,16,24
            const int row = (sub >> 1) * 16 + r;
            const int col = (sub & 1) * 32 + (cc ^ ((r & 8) ? 16 : 0));
            const int off = row * FEAT + col;
            if (i == 0) goff0 = off; else goff1 = off;
        }
    }

    const unsigned short* Ag = xb + (size_t)row0 * FEAT;
    const unsigned short* Bg = wt + (size_t)col0 * FEAT;

#define STAGE(gbase, ldsbase, bufsel, h, kt)                                   \
    do {                                                                       \
        gload16(gbase + (h) * 131072 + (kt) * BK + goff0,                      \
                (ldsbase) + (bufsel) * 32768 + (h) * 16384 + t * 16);          \
        gload16(gbase + (h) * 131072 + (kt) * BK + goff1,                      \
                (ldsbase) + (bufsel) * 32768 + (h) * 16384 + 8192 + t * 16);   \
    } while (0)

    // wave / lane decomposition: 8 waves = 2 (M) x 4 (N); per-wave 128x64 out
    const int wv   = t >> 6;
    const int ln   = t & 63;
    const int wm   = wv >> 2;      // 0..1
    const int wn   = wv & 3;       // 0..3
    const int quad = ln >> 4;      // 0..3
    const int r16  = ln & 15;

    // swizzled per-lane fragment byte base within a subtile
    const int fb = r16 * 64 + ((quad * 8) ^ ((r16 & 8) << 1)) * 2;
    const char* Afb = Abuf + wm * 16384 + fb;   // + cur*32768 + mi*2048 + ks*1024
    const char* Bfb = Bbuf + wn * 8192 + fb;    // + cur*32768 + ni*2048 + ks*1024

    f32x4 acc[8][4];
#pragma unroll
    for (int i = 0; i < 8; ++i)
#pragma unroll
        for (int j = 0; j < 4; ++j) acc[i][j] = (f32x4)0.0f;

    // prologue: B(0), A(0), B(1); vmcnt(4) leaves B(1)'s 4 loads in flight
    STAGE(Bg, Bbuf, 0, 0, 0);
    STAGE(Bg, Bbuf, 0, 1, 0);
    STAGE(Ag, Abuf, 0, 0, 0);
    STAGE(Ag, Abuf, 0, 1, 0);
    STAGE(Bg, Bbuf, 1, 0, 1);
    STAGE(Bg, Bbuf, 1, 1, 1);
    asm volatile("s_waitcnt vmcnt(4)" ::: "memory");
    __builtin_amdgcn_s_barrier();

    short8 a[4][2], b01[2][2], b23[2][2];

#pragma unroll 2
    for (int kt = 0; kt < NT; ++kt) {
        const int cur = kt & 1;
        const char* Ac = Afb + cur * 32768;
        const char* Bc = Bfb + cur * 32768;

        // ---- P1: read a03 + ALL B fragments; stage A0(kt+1); Q00
#pragma unroll
        for (int ni = 0; ni < 2; ++ni)
#pragma unroll
            for (int ks = 0; ks < 2; ++ks) {
                b01[ni][ks] = *(const short8*)(Bc + ni * 2048 + ks * 1024);
                b23[ni][ks] = *(const short8*)(Bc + (ni + 2) * 2048 + ks * 1024);
            }
#pragma unroll
        for (int mi = 0; mi < 4; ++mi)
#pragma unroll
            for (int ks = 0; ks < 2; ++ks)
                a[mi][ks] = *(const short8*)(Ac + mi * 2048 + ks * 1024);
        if (kt + 1 < NT) STAGE(Ag, Abuf, (kt + 1) & 1, 0, kt + 1);
        __builtin_amdgcn_s_setprio(1);
#pragma unroll
        for (int mi = 0; mi < 4; ++mi)
#pragma unroll
            for (int ni = 0; ni < 2; ++ni)
#pragma unroll
                for (int ks = 0; ks < 2; ++ks)
                    acc[mi][ni] = __builtin_amdgcn_mfma_f32_16x16x32_bf16(
                        a[mi][ks], b01[ni][ks], acc[mi][ni], 0, 0, 0);
        __builtin_amdgcn_s_setprio(0);
        // certify ALL waves' B-reads of tile kt (incl. b23) before B(kt+2) staging
        asm volatile("s_waitcnt lgkmcnt(0)" ::: "memory");
        __builtin_amdgcn_s_barrier();               // BAR-A

        // ---- barrier-free run: stages + Q01 + a47 re-read + Q10/Q11
        if (kt + 1 < NT) STAGE(Ag, Abuf, (kt + 1) & 1, 1, kt + 1);
        if (kt + 2 < NT) STAGE(Bg, Bbuf, kt & 1, 0, kt + 2);
        __builtin_amdgcn_s_setprio(1);
#pragma unroll
        for (int mi = 0; mi < 4; ++mi)
#pragma unroll
            for (int ni = 0; ni < 2; ++ni)
#pragma unroll
                for (int ks = 0; ks < 2; ++ks)
                    acc[mi][ni + 2] = __builtin_amdgcn_mfma_f32_16x16x32_bf16(
                        a[mi][ks], b23[ni][ks], acc[mi][ni + 2], 0, 0, 0);
        __builtin_amdgcn_s_setprio(0);
        // re-read a47 into a03's registers (WAR after Q01 consumed a03)
#pragma unroll
        for (int mi = 0; mi < 4; ++mi)
#pragma unroll
            for (int ks = 0; ks < 2; ++ks)
                a[mi][ks] = *(const short8*)(Ac + (mi + 4) * 2048 + ks * 1024);
        if (kt + 2 < NT) STAGE(Bg, Bbuf, kt & 1, 1, kt + 2);
        asm volatile("s_waitcnt lgkmcnt(0)" ::: "memory");
        __builtin_amdgcn_s_setprio(1);
#pragma unroll
        for (int mi = 0; mi < 4; ++mi)
#pragma unroll
            for (int ni = 0; ni < 2; ++ni)
#pragma unroll
                for (int ks = 0; ks < 2; ++ks)
                    acc[mi + 4][ni] = __builtin_amdgcn_mfma_f32_16x16x32_bf16(
                        a[mi][ks], b01[ni][ks], acc[mi + 4][ni], 0, 0, 0);
#pragma unroll
        for (int mi = 0; mi < 4; ++mi)
#pragma unroll
            for (int ni = 0; ni < 2; ++ni)
#pragma unroll
                for (int ks = 0; ks < 2; ++ks)
                    acc[mi + 4][ni + 2] = __builtin_amdgcn_mfma_f32_16x16x32_bf16(
                        a[mi][ks], b23[ni][ks], acc[mi + 4][ni + 2], 0, 0, 0);
        __builtin_amdgcn_s_setprio(0);

        // ---- end of K-tile: counted vmcnt + single re-sync barrier
        if (kt + 2 < NT) {
            asm volatile("s_waitcnt vmcnt(4)" ::: "memory");   // tile kt+1 arrived
        } else if (kt + 1 < NT) {
            asm volatile("s_waitcnt vmcnt(0)" ::: "memory");   // tail drain
        }
        __builtin_amdgcn_s_barrier();               // BAR-END
    }
#undef STAGE

    // epilogue: (acc + bias) * leaf_prob, nontemporal streaming stores
    const float* lpw = lps + (wn >> 1) * 256;
#pragma unroll
    for (int mi = 0; mi < 8; ++mi) {
        const int r = wm * 128 + mi * 16 + quad * 4;
#pragma unroll
        for (int ni = 0; ni < 4; ++ni) {
            const int c  = wn * 64 + ni * 16 + r16;
            const float bv = bs[c];
#pragma unroll
            for (int reg = 0; reg < 4; ++reg) {
                const float v = (acc[mi][ni][reg] + bv) * lpw[r + reg];
                __builtin_nontemporal_store(
                    v, &out[(size_t)(row0 + r + reg) * OUTD + col0 + c]);
            }
        }
    }
}

// ------------------------------- launcher ----------------------------------

extern "C" void kernel_launch(void* const* d_in, const int* in_sizes, int n_in,
                              void* d_out, int out_size, void* d_ws, size_t ws_size,
                              hipStream_t stream) {
    const float* x    = (const float*)d_in[0];   // [8192][1024]
    const float* rw   = (const float*)d_in[1];   // [63][1024][2]
    const float* lw   = (const float*)d_in[2];   // [64][1024][128]
    const float* bias = (const float*)d_in[3];   // [64][128]
    const int*   pn   = (const int*)d_in[4];     // [64][6]
    const int*   pd   = (const int*)d_in[5];     // [64][6]
    float* out = (float*)d_out;

    char* ws = (char*)d_ws;
    unsigned short* xb     = (unsigned short*)(ws);               // 16 MB
    unsigned short* wt     = (unsigned short*)(ws + 16777216);    // 16 MB
    unsigned short* rt     = (unsigned short*)(ws + 33554432);    // 256 KB
    float*          logits = (float*)(ws + 33816576);             // 4 MB
    float*          lpv    = (float*)(ws + 38010880);             // 2 MB

    cvt_x<<<8192, 256, 0, stream>>>(x, xb);
    cvt_lw<<<dim3(64, 32, 4), 256, 0, stream>>>(lw, wt);
    cvt_rw<<<512, 256, 0, stream>>>(rw, rt);
    routing_gemm<<<64, 256, 0, stream>>>(xb, rt, logits);
    leafprob<<<2048, 256, 0, stream>>>(logits, pn, pd, lpv);
    leaf_gemm<<<dim3(1024), 512, 0, stream>>>(xb, wt, lpv, bias, out);
}